// Round 21
// baseline (673.503 us; speedup 1.0000x reference)
//
#include <hip/hip_runtime.h>
#include <hip/hip_bf16.h>

constexpr int D    = 128;   // d_model
constexpr int HF   = 256;   // ffn / out dim
constexpr int NH   = 4;
constexpr int DH   = 32;
constexpr int NL   = 3;
constexpr int SEQ  = 1024;
constexpr int NB   = 65;    // 64 support + 1 query
constexpr int NTOK = NB * SEQ;   // 66560
constexpr int NSUP = 64 * SEQ;   // 65536
constexpr int NC   = 10;

using u16 = unsigned short;
using u32 = unsigned int;
typedef __bf16 bf16x8 __attribute__((ext_vector_type(8)));
typedef float  f32x4  __attribute__((ext_vector_type(4)));
typedef float  f32x16 __attribute__((ext_vector_type(16)));
typedef u16    u16x4  __attribute__((ext_vector_type(4)));
typedef u16    u16x8  __attribute__((ext_vector_type(8)));
typedef u32    u32x2  __attribute__((ext_vector_type(2)));

static __device__ __forceinline__ u16 f2b(float f) {
  return __builtin_bit_cast(u16, (__bf16)f);
}
static __device__ __forceinline__ float b2f(u16 u) {
  return (float)__builtin_bit_cast(__bf16, u);
}

// async global->LDS, 16B per lane; lds base must be wave-uniform
#define GLOAD16(gsrc, ldst) \
  __builtin_amdgcn_global_load_lds( \
      (const __attribute__((address_space(1))) void*)(gsrc), \
      (__attribute__((address_space(3))) void*)(ldst), 16, 0, 0)

// -------- setup: weights f32->bf16 (blocks 0..1663) + embedding (rest) --------
__global__ __launch_bounds__(256) void k_setup(const float* __restrict__ w0,
                                               const float* __restrict__ w1,
                                               const float* __restrict__ w2,
                                               const float* __restrict__ w3,
                                               const float* __restrict__ w4,
                                               u16* __restrict__ wout,
                                               const int* __restrict__ sup,
                                               const int* __restrict__ qry,
                                               const float* __restrict__ emb,
                                               u32* __restrict__ xbw) {
  const int bid = blockIdx.x;
  if (bid < 1664) {
    int i = bid * 256 + threadIdx.x;
    const float* src; int off;
    if      (i < 147456) { src = w0; off = i; }
    else if (i < 196608) { src = w1; off = i - 147456; }
    else if (i < 294912) { src = w2; off = i - 196608; }
    else if (i < 393216) { src = w3; off = i - 294912; }
    else                 { src = w4; off = i - 393216; }
    wout[i] = f2b(src[off]);
  } else {
    int i = (bid - 1664) * 256 + threadIdx.x;     // over NTOK*64 u32 pairs
    int tok = i >> 6;
    int d2 = (i & 63) * 2;
    int t = tok < NSUP ? sup[tok] : qry[tok - NSUP];
    float2 e = *(const float2*)(emb + t * D + d2);
    xbw[i] = (u32)f2b(e.x) | ((u32)f2b(e.y) << 16);
  }
}

// ---------------- MFMA GEMM, K=128, A staged ONCE, n-tiles looped in-kernel ----
// C[m,n] = sum_k A[m,k]*B[n,k] + bias[n]. Grid is 1-D over m-tiles; each block
// stages its 128x128 A panel once (4 x [128][32] sub-buffers), then loops over
// N/128 n-tiles re-staging only B. Removes the 2-3x redundant A staging of the
// old (n,m) grid. Requires K == 128 (all call sites).
template<bool RELU, bool BF16OUT>
__global__ __launch_bounds__(256) void k_gemm_mfma(const u16* __restrict__ A,
                                                   const u16* __restrict__ B,
                                                   const float* __restrict__ bias,
                                                   void* __restrict__ Cm,
                                                   int M, int N) {
  constexpr int K = 128;
  extern __shared__ u16 lds[];
  u16* As = lds;                  // 4 x [128][32] = 16384 u16
  u16* Bs = lds + 16384;
  const int tid = threadIdx.x;
  const int w = tid >> 6, l = tid & 63;
  const int g = l >> 4, c16 = l & 15;
  const int m0 = blockIdx.x * 128;

  const u16* gA = A + (size_t)(m0 + w * 32 + (l >> 2)) * K + (l & 3) * 8;
  const u16* gB = B + (size_t)(w * 32 + (l >> 2)) * K + (l & 3) * 8;
  u16* lA = As + w * 32 * 32;
  u16* lB = Bs + w * 32 * 32;

  // stage A once (loads drained by the first in-loop barrier pair)
  #pragma unroll
  for (int s = 0; s < 4; ++s) {
    GLOAD16(gA + s * 32, lA + s * 4096);
    GLOAD16(gA + (size_t)16 * K + s * 32, lA + s * 4096 + 16 * 32);
  }

  for (int n0 = 0; n0 < N; n0 += 128) {
    __syncthreads();               // prior Bs reads complete before overwrite
    #pragma unroll
    for (int s = 0; s < 4; ++s) {
      GLOAD16(gB + (size_t)n0 * K + s * 32, lB + s * 4096);
      GLOAD16(gB + (size_t)(n0 + 16) * K + s * 32, lB + s * 4096 + 16 * 32);
    }
    __syncthreads();               // barrier drains vmcnt: A (first iter) + B ready

    f32x4 acc[2][8] = {};
    #pragma unroll
    for (int s = 0; s < 4; ++s) {
      const u16* arp = As + s * 4096 + (w * 32 + c16) * 32 + g * 8;
      const u16* brp = Bs + s * 4096 + (size_t)c16 * 32 + g * 8;
      bf16x8 a0 = *(const bf16x8*)(arp);
      bf16x8 a1 = *(const bf16x8*)(arp + 16 * 32);
      #pragma unroll
      for (int nc = 0; nc < 8; ++nc) {
        bf16x8 b = *(const bf16x8*)(brp + nc * 16 * 32);
        acc[0][nc] = __builtin_amdgcn_mfma_f32_16x16x32_bf16(a0, b, acc[0][nc], 0, 0, 0);
        acc[1][nc] = __builtin_amdgcn_mfma_f32_16x16x32_bf16(a1, b, acc[1][nc], 0, 0, 0);
      }
    }

    #pragma unroll
    for (int nc = 0; nc < 8; ++nc) {
      const int n_ = n0 + nc * 16 + c16;
      const float bs = bias[n_];
      #pragma unroll
      for (int mf = 0; mf < 2; ++mf)
        #pragma unroll
        for (int r = 0; r < 4; ++r) {
          const int m_ = m0 + w * 32 + mf * 16 + g * 4 + r;
          float v = acc[mf][nc][r] + bs;
          if (RELU) v = fmaxf(v, 0.f);
          if (BF16OUT) ((u16*)Cm)[(size_t)m_ * N + n_] = f2b(v);
          else         ((float*)Cm)[(size_t)m_ * N + n_] = v;
        }
    }
  }
}

// ------- MFMA GEMM (N=128), full-K staging, fused residual+LN (r19) -------
__global__ __launch_bounds__(256) void k_gemm_ln(const u16* __restrict__ A,
                                                 const u16* __restrict__ B,
                                                 const float* __restrict__ bias,
                                                 u16* __restrict__ xres,
                                                 const float* __restrict__ gamma,
                                                 const float* __restrict__ beta,
                                                 int M, int K) {
  extern __shared__ u16 lds[];
  u16* As = lds;
  u16* Bs = lds + 16384;
  const int tid = threadIdx.x;
  const int w = tid >> 6, l = tid & 63;
  const int g = l >> 4, c16 = l & 15;
  const int m0 = blockIdx.x * 128;

  f32x4 acc[2][8] = {};
  const u16* gA = A + (size_t)(m0 + w * 32 + (l >> 2)) * K + (l & 3) * 8;
  const u16* gB = B + (size_t)(w * 32 + (l >> 2)) * K + (l & 3) * 8;
  u16* lA = As + w * 32 * 32;
  u16* lB = Bs + w * 32 * 32;

  for (int k0 = 0; k0 < K; k0 += 128) {
    __syncthreads();
    #pragma unroll
    for (int s = 0; s < 4; ++s) {
      const int kk = k0 + s * 32;
      GLOAD16(gA + kk, lA + s * 4096);
      GLOAD16(gA + (size_t)16 * K + kk, lA + s * 4096 + 16 * 32);
      GLOAD16(gB + kk, lB + s * 4096);
      GLOAD16(gB + (size_t)16 * K + kk, lB + s * 4096 + 16 * 32);
    }
    __syncthreads();

    #pragma unroll
    for (int s = 0; s < 4; ++s) {
      const u16* arp = As + s * 4096 + (w * 32 + c16) * 32 + g * 8;
      const u16* brp = Bs + s * 4096 + (size_t)c16 * 32 + g * 8;
      bf16x8 a0 = *(const bf16x8*)(arp);
      bf16x8 a1 = *(const bf16x8*)(arp + 16 * 32);
      #pragma unroll
      for (int nc = 0; nc < 8; ++nc) {
        bf16x8 b = *(const bf16x8*)(brp + nc * 16 * 32);
        acc[0][nc] = __builtin_amdgcn_mfma_f32_16x16x32_bf16(a0, b, acc[0][nc], 0, 0, 0);
        acc[1][nc] = __builtin_amdgcn_mfma_f32_16x16x32_bf16(a1, b, acc[1][nc], 0, 0, 0);
      }
    }
  }

  float bsv[8], gms[8], bts[8];
  #pragma unroll
  for (int nc = 0; nc < 8; ++nc) {
    int col = nc * 16 + c16;
    bsv[nc] = bias[col]; gms[nc] = gamma[col]; bts[nc] = beta[col];
  }

  #pragma unroll
  for (int mf = 0; mf < 2; ++mf)
    #pragma unroll
    for (int r = 0; r < 4; ++r) {
      const int row = m0 + w * 32 + mf * 16 + g * 4 + r;
      u16* xrow = xres + (size_t)row * 128;
      float v[8];
      float s = 0.f, q = 0.f;
      #pragma unroll
      for (int nc = 0; nc < 8; ++nc) {
        float t = acc[mf][nc][r] + bsv[nc] + b2f(xrow[nc * 16 + c16]);
        v[nc] = t; s += t; q += t * t;
      }
      #pragma unroll
      for (int off = 8; off; off >>= 1) {
        s += __shfl_xor(s, off);
        q += __shfl_xor(q, off);
      }
      float mean = s * (1.f / 128.f);
      float var  = q * (1.f / 128.f) - mean * mean;
      float invn = 1.f / sqrtf(var + 1e-5f);
      #pragma unroll
      for (int nc = 0; nc < 8; ++nc)
        xrow[nc * 16 + c16] = f2b((v[nc] - mean) * invn * gms[nc] + bts[nc]);
    }
}

// ---------------- MFMA flash attention: dual q-tile (r18, unchanged) ----------
__global__ __launch_bounds__(256) void k_attn_mfma(const u16* __restrict__ qkvb,
                                                   u16* __restrict__ out) {
  const int i = blockIdx.x;
  const int b = (i & 7) + (((i >> 3) >> 4) << 3);
  if (b >= NB) return;
  const int qt = (i >> 3) & 15;
  const int tid = threadIdx.x;
  const int h = tid >> 6;         // wave = head
  const int l = tid & 63;
  const int q5 = l & 31;
  const int hi = l >> 5;          // lane half
  const int qbase = qt * 64;

  __shared__ u16 VtAll[4][2304];  // per-wave V^T [dh][key], stride 72
  u16* Vt = VtAll[h];
  u32* Vtw = (u32*)Vt;

  const size_t tok0 = (size_t)b * SEQ;
  constexpr float KSL = 0.25500446f;   // 1/sqrt(32) * log2(e)

  const u16* qrowA = qkvb + (tok0 + qbase + q5) * 384 + h * 32 + hi * 8;
  bf16x8 qA0 = *(const bf16x8*)(qrowA);
  bf16x8 qA1 = *(const bf16x8*)(qrowA + 16);
  const u16* qrowB = qrowA + (size_t)32 * 384;
  bf16x8 qB0 = *(const bf16x8*)(qrowB);
  bf16x8 qB1 = *(const bf16x8*)(qrowB + 16);

  f32x16 accA = {}, accB = {};
  float lsA = 0.f, lsB = 0.f;

  const u16* kbase = qkvb + tok0 * 384 + 128 + h * 32 + (size_t)q5 * 384 + hi * 8;
  const u16* vbase = qkvb + tok0 * 384 + 256 + h * 32 + hi * 16;
  const f32x16 z16 = {};

  for (int kt = 0; kt < SEQ; kt += 64) {
    const u16* vr0 = vbase + (size_t)(kt + q5 * 2) * 384;
    const u16* vr1 = vr0 + 384;
    u16x8 a_lo = *(const u16x8*)(vr0);
    u16x8 a_hi = *(const u16x8*)(vr0 + 8);
    u16x8 b_lo = *(const u16x8*)(vr1);
    u16x8 b_hi = *(const u16x8*)(vr1 + 8);
    const u16* kr = kbase + (size_t)kt * 384;
    bf16x8 k00 = *(const bf16x8*)(kr);
    bf16x8 k01 = *(const bf16x8*)(kr + 16);
    bf16x8 k10 = *(const bf16x8*)(kr + (size_t)32 * 384);
    bf16x8 k11 = *(const bf16x8*)(kr + (size_t)32 * 384 + 16);

    #pragma unroll
    for (int j = 0; j < 8; ++j) {
      Vtw[(hi * 16 + j) * 36 + q5]     = (u32)a_lo[j] | ((u32)b_lo[j] << 16);
      Vtw[(hi * 16 + 8 + j) * 36 + q5] = (u32)a_hi[j] | ((u32)b_hi[j] << 16);
    }
    // no fence: wave-private LDS, DS ops in-order within a wave

    f32x16 sA0 = __builtin_amdgcn_mfma_f32_32x32x16_bf16(k00, qA0, z16, 0, 0, 0);
    sA0 = __builtin_amdgcn_mfma_f32_32x32x16_bf16(k01, qA1, sA0, 0, 0, 0);
    f32x16 sA1 = __builtin_amdgcn_mfma_f32_32x32x16_bf16(k10, qA0, z16, 0, 0, 0);
    sA1 = __builtin_amdgcn_mfma_f32_32x32x16_bf16(k11, qA1, sA1, 0, 0, 0);
    f32x16 sB0 = __builtin_amdgcn_mfma_f32_32x32x16_bf16(k00, qB0, z16, 0, 0, 0);
    sB0 = __builtin_amdgcn_mfma_f32_32x32x16_bf16(k01, qB1, sB0, 0, 0, 0);
    f32x16 sB1 = __builtin_amdgcn_mfma_f32_32x32x16_bf16(k10, qB0, z16, 0, 0, 0);
    sB1 = __builtin_amdgcn_mfma_f32_32x32x16_bf16(k11, qB1, sB1, 0, 0, 0);

    u32 pkA0[8], pkA1[8], pkB0[8], pkB1[8];
    {
      float ps0 = 0.f, ps1 = 0.f;
      #pragma unroll
      for (int mi = 0; mi < 8; ++mi) {
        float e0 = __builtin_amdgcn_exp2f(sA0[2 * mi] * KSL);
        float e1 = __builtin_amdgcn_exp2f(sA0[2 * mi + 1] * KSL);
        float e2 = __builtin_amdgcn_exp2f(sA1[2 * mi] * KSL);
        float e3 = __builtin_amdgcn_exp2f(sA1[2 * mi + 1] * KSL);
        ps0 += e0 + e1; ps1 += e2 + e3;
        pkA0[mi] = (u32)f2b(e0) | ((u32)f2b(e1) << 16);
        pkA1[mi] = (u32)f2b(e2) | ((u32)f2b(e3) << 16);
      }
      lsA += ps0 + ps1;
    }
    {
      float ps0 = 0.f, ps1 = 0.f;
      #pragma unroll
      for (int mi = 0; mi < 8; ++mi) {
        float e0 = __builtin_amdgcn_exp2f(sB0[2 * mi] * KSL);
        float e1 = __builtin_amdgcn_exp2f(sB0[2 * mi + 1] * KSL);
        float e2 = __builtin_amdgcn_exp2f(sB1[2 * mi] * KSL);
        float e3 = __builtin_amdgcn_exp2f(sB1[2 * mi + 1] * KSL);
        ps0 += e0 + e1; ps1 += e2 + e3;
        pkB0[mi] = (u32)f2b(e0) | ((u32)f2b(e1) << 16);
        pkB1[mi] = (u32)f2b(e2) | ((u32)f2b(e3) << 16);
      }
      lsB += ps0 + ps1;
    }

    #pragma unroll
    for (int t = 0; t < 2; ++t) {
      #pragma unroll
      for (int hh = 0; hh < 2; ++hh) {
        bf16x8 vf = *(const bf16x8*)(Vt + (size_t)q5 * 72 + t * 32 + hh * 16 + hi * 8);
        {
          u32 a0w = t ? pkA1[4 * hh + 0] : pkA0[4 * hh + 0];
          u32 a1w = t ? pkA1[4 * hh + 1] : pkA0[4 * hh + 1];
          u32 a2w = t ? pkA1[4 * hh + 2] : pkA0[4 * hh + 2];
          u32 a3w = t ? pkA1[4 * hh + 3] : pkA0[4 * hh + 3];
          u32x2 r02 = __builtin_amdgcn_permlane32_swap(a0w, a2w, false, false);
          u32x2 r13 = __builtin_amdgcn_permlane32_swap(a1w, a3w, false, false);
          union { u32 w[4]; bf16x8 v; } pf;
          pf.w[0] = r02.x; pf.w[1] = r13.x; pf.w[2] = r02.y; pf.w[3] = r13.y;
          accA = __builtin_amdgcn_mfma_f32_32x32x16_bf16(vf, pf.v, accA, 0, 0, 0);
        }
        {
          u32 a0w = t ? pkB1[4 * hh + 0] : pkB0[4 * hh + 0];
          u32 a1w = t ? pkB1[4 * hh + 1] : pkB0[4 * hh + 1];
          u32 a2w = t ? pkB1[4 * hh + 2] : pkB0[4 * hh + 2];
          u32 a3w = t ? pkB1[4 * hh + 3] : pkB0[4 * hh + 3];
          u32x2 r02 = __builtin_amdgcn_permlane32_swap(a0w, a2w, false, false);
          u32x2 r13 = __builtin_amdgcn_permlane32_swap(a1w, a3w, false, false);
          union { u32 w[4]; bf16x8 v; } pf;
          pf.w[0] = r02.x; pf.w[1] = r13.x; pf.w[2] = r02.y; pf.w[3] = r13.y;
          accB = __builtin_amdgcn_mfma_f32_32x32x16_bf16(vf, pf.v, accB, 0, 0, 0);
        }
      }
    }
  }

  lsA += __shfl_xor(lsA, 32);
  lsB += __shfl_xor(lsB, 32);
  float invA = 1.f / lsA, invB = 1.f / lsB;
  u16* orowA = out + (tok0 + qbase + q5) * 128 + h * 32 + hi * 4;
  u16* orowB = orowA + (size_t)32 * 128;
  #pragma unroll
  for (int a = 0; a < 4; ++a) {
    u16x4 stA, stB;
    #pragma unroll
    for (int j = 0; j < 4; ++j) {
      stA[j] = f2b(accA[a * 4 + j] * invA);
      stB[j] = f2b(accB[a * 4 + j] * invB);
    }
    *(u16x4*)(orowA + a * 8) = stA;
    *(u16x4*)(orowB + a * 8) = stB;
  }
}

// ---------------- prototype accumulation (bf16 feat) ----------------
__global__ __launch_bounds__(256) void k_proto_accum(const u16* __restrict__ feat,
                                                     const int* __restrict__ cls,
                                                     const int* __restrict__ msk,
                                                     float* __restrict__ psum,
                                                     int* __restrict__ pcnt) {
  __shared__ float ls[NC][HF];
  __shared__ int lc[NC];
  int tid = threadIdx.x;
  #pragma unroll
  for (int c = 0; c < NC; ++c) ls[c][tid] = 0.f;
  if (tid < NC) lc[tid] = 0;
  __syncthreads();
  int t0 = blockIdx.x * 256;
  for (int t = t0; t < t0 + 256; ++t) {
    int cl = cls[t];
    int mk = msk[t];
    if (mk > 0 && cl < NC) {
      ls[cl][tid] += b2f(feat[(size_t)t * HF + tid]);
      if (tid == 0) lc[cl]++;
    }
  }
  __syncthreads();
  for (int c = 0; c < NC; ++c) atomicAdd(&psum[c * HF + tid], ls[c][tid]);
  if (tid < NC) atomicAdd(&pcnt[tid], lc[tid]);
}

// ---------------- logits with fused prototype finalization ----------------
__global__ __launch_bounds__(256) void k_logits(const u16* __restrict__ feat,
                                                const float* __restrict__ psum,
                                                const int* __restrict__ pcnt,
                                                float* __restrict__ out) {
  __shared__ float pl[NC * HF];
  const int tid = threadIdx.x;
  #pragma unroll
  for (int j = 0; j < NC * HF / 256; ++j) {
    int idx = j * 256 + tid;
    int c = idx >> 8;
    int n = pcnt[c];
    pl[idx] = (n > 0) ? psum[idx] / (float)n : 0.f;
  }
  __syncthreads();

  int i = blockIdx.x * 256 + tid;
  if (i >= SEQ * NC) return;
  int s = i / NC, c = i % NC;
  const u16* qf = feat + (size_t)(NSUP + s) * HF;
  const float* pr = pl + c * HF;
  float acc = 0.f;
  for (int hh = 0; hh < 32; ++hh) {
    u16x8 v = *(const u16x8*)(qf + hh * 8);
    #pragma unroll
    for (int j = 0; j < 8; ++j) {
      float d = b2f(v[j]) - pr[hh * 8 + j];
      acc += d * d;
    }
  }
  out[i] = -acc;
}

extern "C" void kernel_launch(void* const* d_in, const int* in_sizes, int n_in,
                              void* d_out, int out_size, void* d_ws, size_t ws_size,
                              hipStream_t stream) {
  const int*   sup_in  = (const int*)d_in[0];
  const int*   sup_out = (const int*)d_in[1];
  const int*   qry_in  = (const int*)d_in[2];
  const int*   sup_msk = (const int*)d_in[3];
  const float* emb     = (const float*)d_in[4];
  const float* Wqkv    = (const float*)d_in[5];
  const float* bqkv    = (const float*)d_in[6];
  const float* Wo      = (const float*)d_in[7];
  const float* bo      = (const float*)d_in[8];
  const float* ln1s    = (const float*)d_in[9];
  const float* ln1b    = (const float*)d_in[10];
  const float* W1      = (const float*)d_in[11];
  const float* b1      = (const float*)d_in[12];
  const float* W2      = (const float*)d_in[13];
  const float* b2      = (const float*)d_in[14];
  const float* ln2s    = (const float*)d_in[15];
  const float* ln2b    = (const float*)d_in[16];
  const float* Wp      = (const float*)d_in[17];
  const float* bp      = (const float*)d_in[18];

  // bf16 stream: xb[NTOK,128] | yb[NTOK,128] | U[NTOK,384] | weights | proto scratch
  u16* xb = (u16*)d_ws;
  u16* yb = xb + (size_t)NTOK * D;
  u16* U  = yb + (size_t)NTOK * D;
  u16* qkvb  = U;                                // [NTOK,384]
  u16* midb  = U;                                // [NTOK,256] (qkvb dead)
  u16* featb = U;                                // [NTOK,256]
  u16* wqkvb = U + (size_t)NTOK * 384;
  u16* wob   = wqkvb + 3 * 384 * 128;
  u16* w1b   = wob + 3 * 128 * 128;
  u16* w2b   = w1b + 3 * 256 * 128;
  u16* wpb   = w2b + 3 * 128 * 256;
  float* psum  = (float*)(((size_t)(wpb + 256 * 128) + 15) & ~(size_t)15);
  int*   pcnt  = (int*)(psum + NC * HF);
  float* outp = (float*)d_out;

  constexpr size_t GEMM_LDS = 65536;   // 2 x 4 x [128][32] u16

  hipMemsetAsync(psum, 0, NC * HF * sizeof(float) + 16 * sizeof(int), stream);

  // setup: weight conversion (1664 blocks) + embedding (16640 blocks)
  k_setup<<<dim3(1664 + 16640), 256, 0, stream>>>(
      Wqkv, Wo, W1, W2, Wp, wqkvb, sup_in, qry_in, emb, (u32*)xb);

  for (int l = 0; l < NL; ++l) {
    // QKV: xb -> qkvb (N=384, n-tiles looped, A staged once)
    k_gemm_mfma<false, true><<<dim3(NTOK / 128), 256, GEMM_LDS, stream>>>(
        xb, wqkvb + (size_t)l * 384 * 128, bqkv + l * 384, qkvb, NTOK, 384);
    // attention: qkvb -> yb (dual q-tile)
    k_attn_mfma<<<dim3(1152), 256, 0, stream>>>(qkvb, yb);
    // Wo + residual + LN1 (in place on xb)
    k_gemm_ln<<<dim3(NTOK / 128), 256, GEMM_LDS, stream>>>(
        yb, wob + (size_t)l * 128 * 128, bo + l * D, xb,
        ln1s + l * D, ln1b + l * D, NTOK, D);
    // W1 (+relu): xb -> midb (N=256)
    k_gemm_mfma<true, true><<<dim3(NTOK / 128), 256, GEMM_LDS, stream>>>(
        xb, w1b + (size_t)l * 256 * 128, b1 + l * HF, midb, NTOK, HF);
    // W2 + residual + LN2 (in place on xb)
    k_gemm_ln<<<dim3(NTOK / 128), 256, GEMM_LDS, stream>>>(
        midb, w2b + (size_t)l * 128 * 256, b2 + l * D, xb,
        ln2s + l * D, ln2b + l * D, NTOK, HF);
  }

  // final projection: xb -> featb (N=256)
  k_gemm_mfma<false, true><<<dim3(NTOK / 128), 256, GEMM_LDS, stream>>>(
      xb, wpb, bp, featb, NTOK, HF);
  k_proto_accum<<<dim3(NSUP / 256), 256, 0, stream>>>(featb, sup_out, sup_msk, psum, pcnt);
  k_logits<<<dim3((SEQ * NC + 255) / 256), 256, 0, stream>>>(featb, psum, pcnt, outp);
}

// Round 22
// 635.850 us; speedup vs baseline: 1.0592x; 1.0592x over previous
//
#include <hip/hip_runtime.h>
#include <hip/hip_bf16.h>

constexpr int D    = 128;   // d_model
constexpr int HF   = 256;   // ffn / out dim
constexpr int NH   = 4;
constexpr int DH   = 32;
constexpr int NL   = 3;
constexpr int SEQ  = 1024;
constexpr int NB   = 65;    // 64 support + 1 query
constexpr int NTOK = NB * SEQ;   // 66560
constexpr int NSUP = 64 * SEQ;   // 65536
constexpr int NC   = 10;

using u16 = unsigned short;
using u32 = unsigned int;
typedef __bf16 bf16x8 __attribute__((ext_vector_type(8)));
typedef float  f32x4  __attribute__((ext_vector_type(4)));
typedef float  f32x16 __attribute__((ext_vector_type(16)));
typedef u16    u16x4  __attribute__((ext_vector_type(4)));
typedef u16    u16x8  __attribute__((ext_vector_type(8)));
typedef u32    u32x2  __attribute__((ext_vector_type(2)));

static __device__ __forceinline__ u16 f2b(float f) {
  return __builtin_bit_cast(u16, (__bf16)f);
}
static __device__ __forceinline__ float b2f(u16 u) {
  return (float)__builtin_bit_cast(__bf16, u);
}

// async global->LDS, 16B per lane; lds base must be wave-uniform
#define GLOAD16(gsrc, ldst) \
  __builtin_amdgcn_global_load_lds( \
      (const __attribute__((address_space(1))) void*)(gsrc), \
      (__attribute__((address_space(3))) void*)(ldst), 16, 0, 0)

// -------- setup: weights f32->bf16 (blocks 0..1663) + embedding (rest) --------
__global__ __launch_bounds__(256) void k_setup(const float* __restrict__ w0,
                                               const float* __restrict__ w1,
                                               const float* __restrict__ w2,
                                               const float* __restrict__ w3,
                                               const float* __restrict__ w4,
                                               u16* __restrict__ wout,
                                               const int* __restrict__ sup,
                                               const int* __restrict__ qry,
                                               const float* __restrict__ emb,
                                               u32* __restrict__ xbw) {
  const int bid = blockIdx.x;
  if (bid < 1664) {
    int i = bid * 256 + threadIdx.x;
    const float* src; int off;
    if      (i < 147456) { src = w0; off = i; }
    else if (i < 196608) { src = w1; off = i - 147456; }
    else if (i < 294912) { src = w2; off = i - 196608; }
    else if (i < 393216) { src = w3; off = i - 294912; }
    else                 { src = w4; off = i - 393216; }
    wout[i] = f2b(src[off]);
  } else {
    int i = (bid - 1664) * 256 + threadIdx.x;     // over NTOK*64 u32 pairs
    int tok = i >> 6;
    int d2 = (i & 63) * 2;
    int t = tok < NSUP ? sup[tok] : qry[tok - NSUP];
    float2 e = *(const float2*)(emb + t * D + d2);
    xbw[i] = (u32)f2b(e.x) | ((u32)f2b(e.y) << 16);
  }
}

// ---------------- MFMA GEMM, full-K LDS staging (r19/r20) ----------------
template<bool RELU, bool BF16OUT>
__global__ __launch_bounds__(256) void k_gemm_mfma(const u16* __restrict__ A,
                                                   const u16* __restrict__ B,
                                                   const float* __restrict__ bias,
                                                   void* __restrict__ Cm,
                                                   int M, int N, int K) {
  extern __shared__ u16 lds[];
  u16* As = lds;                  // 4 x [128][32] = 16384 u16
  u16* Bs = lds + 16384;
  const int tid = threadIdx.x;
  const int w = tid >> 6, l = tid & 63;
  const int g = l >> 4, c16 = l & 15;
  const int m0 = blockIdx.y * 128;
  const int n0 = blockIdx.x * 128;

  f32x4 acc[2][8] = {};
  const u16* gA = A + (size_t)(m0 + w * 32 + (l >> 2)) * K + (l & 3) * 8;
  const u16* gB = B + (size_t)(n0 + w * 32 + (l >> 2)) * K + (l & 3) * 8;
  u16* lA = As + w * 32 * 32;
  u16* lB = Bs + w * 32 * 32;

  for (int k0 = 0; k0 < K; k0 += 128) {
    __syncthreads();
    #pragma unroll
    for (int s = 0; s < 4; ++s) {
      const int kk = k0 + s * 32;
      GLOAD16(gA + kk, lA + s * 4096);
      GLOAD16(gA + (size_t)16 * K + kk, lA + s * 4096 + 16 * 32);
      GLOAD16(gB + kk, lB + s * 4096);
      GLOAD16(gB + (size_t)16 * K + kk, lB + s * 4096 + 16 * 32);
    }
    __syncthreads();

    #pragma unroll
    for (int s = 0; s < 4; ++s) {
      const u16* arp = As + s * 4096 + (w * 32 + c16) * 32 + g * 8;
      const u16* brp = Bs + s * 4096 + (size_t)c16 * 32 + g * 8;
      bf16x8 a0 = *(const bf16x8*)(arp);
      bf16x8 a1 = *(const bf16x8*)(arp + 16 * 32);
      #pragma unroll
      for (int nc = 0; nc < 8; ++nc) {
        bf16x8 b = *(const bf16x8*)(brp + nc * 16 * 32);
        acc[0][nc] = __builtin_amdgcn_mfma_f32_16x16x32_bf16(a0, b, acc[0][nc], 0, 0, 0);
        acc[1][nc] = __builtin_amdgcn_mfma_f32_16x16x32_bf16(a1, b, acc[1][nc], 0, 0, 0);
      }
    }
  }

  #pragma unroll
  for (int nc = 0; nc < 8; ++nc) {
    const int n_ = n0 + nc * 16 + c16;
    const float bs = bias[n_];
    #pragma unroll
    for (int mf = 0; mf < 2; ++mf)
      #pragma unroll
      for (int r = 0; r < 4; ++r) {
        const int m_ = m0 + w * 32 + mf * 16 + g * 4 + r;
        float v = acc[mf][nc][r] + bs;
        if (RELU) v = fmaxf(v, 0.f);
        if (BF16OUT) ((u16*)Cm)[(size_t)m_ * N + n_] = f2b(v);
        else         ((float*)Cm)[(size_t)m_ * N + n_] = v;
      }
  }
}

// ------- MFMA GEMM (N=128), full-K staging, fused residual+LN (r19/r20) -------
__global__ __launch_bounds__(256) void k_gemm_ln(const u16* __restrict__ A,
                                                 const u16* __restrict__ B,
                                                 const float* __restrict__ bias,
                                                 u16* __restrict__ xres,
                                                 const float* __restrict__ gamma,
                                                 const float* __restrict__ beta,
                                                 int M, int K) {
  extern __shared__ u16 lds[];
  u16* As = lds;
  u16* Bs = lds + 16384;
  const int tid = threadIdx.x;
  const int w = tid >> 6, l = tid & 63;
  const int g = l >> 4, c16 = l & 15;
  const int m0 = blockIdx.x * 128;

  f32x4 acc[2][8] = {};
  const u16* gA = A + (size_t)(m0 + w * 32 + (l >> 2)) * K + (l & 3) * 8;
  const u16* gB = B + (size_t)(w * 32 + (l >> 2)) * K + (l & 3) * 8;
  u16* lA = As + w * 32 * 32;
  u16* lB = Bs + w * 32 * 32;

  for (int k0 = 0; k0 < K; k0 += 128) {
    __syncthreads();
    #pragma unroll
    for (int s = 0; s < 4; ++s) {
      const int kk = k0 + s * 32;
      GLOAD16(gA + kk, lA + s * 4096);
      GLOAD16(gA + (size_t)16 * K + kk, lA + s * 4096 + 16 * 32);
      GLOAD16(gB + kk, lB + s * 4096);
      GLOAD16(gB + (size_t)16 * K + kk, lB + s * 4096 + 16 * 32);
    }
    __syncthreads();

    #pragma unroll
    for (int s = 0; s < 4; ++s) {
      const u16* arp = As + s * 4096 + (w * 32 + c16) * 32 + g * 8;
      const u16* brp = Bs + s * 4096 + (size_t)c16 * 32 + g * 8;
      bf16x8 a0 = *(const bf16x8*)(arp);
      bf16x8 a1 = *(const bf16x8*)(arp + 16 * 32);
      #pragma unroll
      for (int nc = 0; nc < 8; ++nc) {
        bf16x8 b = *(const bf16x8*)(brp + nc * 16 * 32);
        acc[0][nc] = __builtin_amdgcn_mfma_f32_16x16x32_bf16(a0, b, acc[0][nc], 0, 0, 0);
        acc[1][nc] = __builtin_amdgcn_mfma_f32_16x16x32_bf16(a1, b, acc[1][nc], 0, 0, 0);
      }
    }
  }

  float bsv[8], gms[8], bts[8];
  #pragma unroll
  for (int nc = 0; nc < 8; ++nc) {
    int col = nc * 16 + c16;
    bsv[nc] = bias[col]; gms[nc] = gamma[col]; bts[nc] = beta[col];
  }

  #pragma unroll
  for (int mf = 0; mf < 2; ++mf)
    #pragma unroll
    for (int r = 0; r < 4; ++r) {
      const int row = m0 + w * 32 + mf * 16 + g * 4 + r;
      u16* xrow = xres + (size_t)row * 128;
      float v[8];
      float s = 0.f, q = 0.f;
      #pragma unroll
      for (int nc = 0; nc < 8; ++nc) {
        float t = acc[mf][nc][r] + bsv[nc] + b2f(xrow[nc * 16 + c16]);
        v[nc] = t; s += t; q += t * t;
      }
      #pragma unroll
      for (int off = 8; off; off >>= 1) {
        s += __shfl_xor(s, off);
        q += __shfl_xor(q, off);
      }
      float mean = s * (1.f / 128.f);
      float var  = q * (1.f / 128.f) - mean * mean;
      float invn = 1.f / sqrtf(var + 1e-5f);
      #pragma unroll
      for (int nc = 0; nc < 8; ++nc)
        xrow[nc * 16 + c16] = f2b((v[nc] - mean) * invn * gms[nc] + bts[nc]);
    }
}

// ---------------- MFMA flash attention: dual q-tile (r18, unchanged) ----------
__global__ __launch_bounds__(256) void k_attn_mfma(const u16* __restrict__ qkvb,
                                                   u16* __restrict__ out) {
  const int i = blockIdx.x;
  const int b = (i & 7) + (((i >> 3) >> 4) << 3);
  if (b >= NB) return;
  const int qt = (i >> 3) & 15;
  const int tid = threadIdx.x;
  const int h = tid >> 6;         // wave = head
  const int l = tid & 63;
  const int q5 = l & 31;
  const int hi = l >> 5;          // lane half
  const int qbase = qt * 64;

  __shared__ u16 VtAll[4][2304];  // per-wave V^T [dh][key], stride 72
  u16* Vt = VtAll[h];
  u32* Vtw = (u32*)Vt;

  const size_t tok0 = (size_t)b * SEQ;
  constexpr float KSL = 0.25500446f;   // 1/sqrt(32) * log2(e)

  const u16* qrowA = qkvb + (tok0 + qbase + q5) * 384 + h * 32 + hi * 8;
  bf16x8 qA0 = *(const bf16x8*)(qrowA);
  bf16x8 qA1 = *(const bf16x8*)(qrowA + 16);
  const u16* qrowB = qrowA + (size_t)32 * 384;
  bf16x8 qB0 = *(const bf16x8*)(qrowB);
  bf16x8 qB1 = *(const bf16x8*)(qrowB + 16);

  f32x16 accA = {}, accB = {};
  float lsA = 0.f, lsB = 0.f;

  const u16* kbase = qkvb + tok0 * 384 + 128 + h * 32 + (size_t)q5 * 384 + hi * 8;
  const u16* vbase = qkvb + tok0 * 384 + 256 + h * 32 + hi * 16;
  const f32x16 z16 = {};

  for (int kt = 0; kt < SEQ; kt += 64) {
    const u16* vr0 = vbase + (size_t)(kt + q5 * 2) * 384;
    const u16* vr1 = vr0 + 384;
    u16x8 a_lo = *(const u16x8*)(vr0);
    u16x8 a_hi = *(const u16x8*)(vr0 + 8);
    u16x8 b_lo = *(const u16x8*)(vr1);
    u16x8 b_hi = *(const u16x8*)(vr1 + 8);
    const u16* kr = kbase + (size_t)kt * 384;
    bf16x8 k00 = *(const bf16x8*)(kr);
    bf16x8 k01 = *(const bf16x8*)(kr + 16);
    bf16x8 k10 = *(const bf16x8*)(kr + (size_t)32 * 384);
    bf16x8 k11 = *(const bf16x8*)(kr + (size_t)32 * 384 + 16);

    #pragma unroll
    for (int j = 0; j < 8; ++j) {
      Vtw[(hi * 16 + j) * 36 + q5]     = (u32)a_lo[j] | ((u32)b_lo[j] << 16);
      Vtw[(hi * 16 + 8 + j) * 36 + q5] = (u32)a_hi[j] | ((u32)b_hi[j] << 16);
    }
    // no fence: wave-private LDS, DS ops in-order within a wave

    f32x16 sA0 = __builtin_amdgcn_mfma_f32_32x32x16_bf16(k00, qA0, z16, 0, 0, 0);
    sA0 = __builtin_amdgcn_mfma_f32_32x32x16_bf16(k01, qA1, sA0, 0, 0, 0);
    f32x16 sA1 = __builtin_amdgcn_mfma_f32_32x32x16_bf16(k10, qA0, z16, 0, 0, 0);
    sA1 = __builtin_amdgcn_mfma_f32_32x32x16_bf16(k11, qA1, sA1, 0, 0, 0);
    f32x16 sB0 = __builtin_amdgcn_mfma_f32_32x32x16_bf16(k00, qB0, z16, 0, 0, 0);
    sB0 = __builtin_amdgcn_mfma_f32_32x32x16_bf16(k01, qB1, sB0, 0, 0, 0);
    f32x16 sB1 = __builtin_amdgcn_mfma_f32_32x32x16_bf16(k10, qB0, z16, 0, 0, 0);
    sB1 = __builtin_amdgcn_mfma_f32_32x32x16_bf16(k11, qB1, sB1, 0, 0, 0);

    u32 pkA0[8], pkA1[8], pkB0[8], pkB1[8];
    {
      float ps0 = 0.f, ps1 = 0.f;
      #pragma unroll
      for (int mi = 0; mi < 8; ++mi) {
        float e0 = __builtin_amdgcn_exp2f(sA0[2 * mi] * KSL);
        float e1 = __builtin_amdgcn_exp2f(sA0[2 * mi + 1] * KSL);
        float e2 = __builtin_amdgcn_exp2f(sA1[2 * mi] * KSL);
        float e3 = __builtin_amdgcn_exp2f(sA1[2 * mi + 1] * KSL);
        ps0 += e0 + e1; ps1 += e2 + e3;
        pkA0[mi] = (u32)f2b(e0) | ((u32)f2b(e1) << 16);
        pkA1[mi] = (u32)f2b(e2) | ((u32)f2b(e3) << 16);
      }
      lsA += ps0 + ps1;
    }
    {
      float ps0 = 0.f, ps1 = 0.f;
      #pragma unroll
      for (int mi = 0; mi < 8; ++mi) {
        float e0 = __builtin_amdgcn_exp2f(sB0[2 * mi] * KSL);
        float e1 = __builtin_amdgcn_exp2f(sB0[2 * mi + 1] * KSL);
        float e2 = __builtin_amdgcn_exp2f(sB1[2 * mi] * KSL);
        float e3 = __builtin_amdgcn_exp2f(sB1[2 * mi + 1] * KSL);
        ps0 += e0 + e1; ps1 += e2 + e3;
        pkB0[mi] = (u32)f2b(e0) | ((u32)f2b(e1) << 16);
        pkB1[mi] = (u32)f2b(e2) | ((u32)f2b(e3) << 16);
      }
      lsB += ps0 + ps1;
    }

    #pragma unroll
    for (int t = 0; t < 2; ++t) {
      #pragma unroll
      for (int hh = 0; hh < 2; ++hh) {
        bf16x8 vf = *(const bf16x8*)(Vt + (size_t)q5 * 72 + t * 32 + hh * 16 + hi * 8);
        {
          u32 a0w = t ? pkA1[4 * hh + 0] : pkA0[4 * hh + 0];
          u32 a1w = t ? pkA1[4 * hh + 1] : pkA0[4 * hh + 1];
          u32 a2w = t ? pkA1[4 * hh + 2] : pkA0[4 * hh + 2];
          u32 a3w = t ? pkA1[4 * hh + 3] : pkA0[4 * hh + 3];
          u32x2 r02 = __builtin_amdgcn_permlane32_swap(a0w, a2w, false, false);
          u32x2 r13 = __builtin_amdgcn_permlane32_swap(a1w, a3w, false, false);
          union { u32 w[4]; bf16x8 v; } pf;
          pf.w[0] = r02.x; pf.w[1] = r13.x; pf.w[2] = r02.y; pf.w[3] = r13.y;
          accA = __builtin_amdgcn_mfma_f32_32x32x16_bf16(vf, pf.v, accA, 0, 0, 0);
        }
        {
          u32 a0w = t ? pkB1[4 * hh + 0] : pkB0[4 * hh + 0];
          u32 a1w = t ? pkB1[4 * hh + 1] : pkB0[4 * hh + 1];
          u32 a2w = t ? pkB1[4 * hh + 2] : pkB0[4 * hh + 2];
          u32 a3w = t ? pkB1[4 * hh + 3] : pkB0[4 * hh + 3];
          u32x2 r02 = __builtin_amdgcn_permlane32_swap(a0w, a2w, false, false);
          u32x2 r13 = __builtin_amdgcn_permlane32_swap(a1w, a3w, false, false);
          union { u32 w[4]; bf16x8 v; } pf;
          pf.w[0] = r02.x; pf.w[1] = r13.x; pf.w[2] = r02.y; pf.w[3] = r13.y;
          accB = __builtin_amdgcn_mfma_f32_32x32x16_bf16(vf, pf.v, accB, 0, 0, 0);
        }
      }
    }
  }

  lsA += __shfl_xor(lsA, 32);
  lsB += __shfl_xor(lsB, 32);
  float invA = 1.f / lsA, invB = 1.f / lsB;
  u16* orowA = out + (tok0 + qbase + q5) * 128 + h * 32 + hi * 4;
  u16* orowB = orowA + (size_t)32 * 128;
  #pragma unroll
  for (int a = 0; a < 4; ++a) {
    u16x4 stA, stB;
    #pragma unroll
    for (int j = 0; j < 4; ++j) {
      stA[j] = f2b(accA[a * 4 + j] * invA);
      stB[j] = f2b(accB[a * 4 + j] * invB);
    }
    *(u16x4*)(orowA + a * 8) = stA;
    *(u16x4*)(orowB + a * 8) = stB;
  }
}

// ---------------- prototype accumulation (bf16 feat) ----------------
__global__ __launch_bounds__(256) void k_proto_accum(const u16* __restrict__ feat,
                                                     const int* __restrict__ cls,
                                                     const int* __restrict__ msk,
                                                     float* __restrict__ psum,
                                                     int* __restrict__ pcnt) {
  __shared__ float ls[NC][HF];
  __shared__ int lc[NC];
  int tid = threadIdx.x;
  #pragma unroll
  for (int c = 0; c < NC; ++c) ls[c][tid] = 0.f;
  if (tid < NC) lc[tid] = 0;
  __syncthreads();
  int t0 = blockIdx.x * 256;
  for (int t = t0; t < t0 + 256; ++t) {
    int cl = cls[t];
    int mk = msk[t];
    if (mk > 0 && cl < NC) {
      ls[cl][tid] += b2f(feat[(size_t)t * HF + tid]);
      if (tid == 0) lc[cl]++;
    }
  }
  __syncthreads();
  for (int c = 0; c < NC; ++c) atomicAdd(&psum[c * HF + tid], ls[c][tid]);
  if (tid < NC) atomicAdd(&pcnt[tid], lc[tid]);
}

// ---------------- logits with fused prototype finalization ----------------
__global__ __launch_bounds__(256) void k_logits(const u16* __restrict__ feat,
                                                const float* __restrict__ psum,
                                                const int* __restrict__ pcnt,
                                                float* __restrict__ out) {
  __shared__ float pl[NC * HF];
  const int tid = threadIdx.x;
  #pragma unroll
  for (int j = 0; j < NC * HF / 256; ++j) {
    int idx = j * 256 + tid;
    int c = idx >> 8;
    int n = pcnt[c];
    pl[idx] = (n > 0) ? psum[idx] / (float)n : 0.f;
  }
  __syncthreads();

  int i = blockIdx.x * 256 + tid;
  if (i >= SEQ * NC) return;
  int s = i / NC, c = i % NC;
  const u16* qf = feat + (size_t)(NSUP + s) * HF;
  const float* pr = pl + c * HF;
  float acc = 0.f;
  for (int hh = 0; hh < 32; ++hh) {
    u16x8 v = *(const u16x8*)(qf + hh * 8);
    #pragma unroll
    for (int j = 0; j < 8; ++j) {
      float d = b2f(v[j]) - pr[hh * 8 + j];
      acc += d * d;
    }
  }
  out[i] = -acc;
}

extern "C" void kernel_launch(void* const* d_in, const int* in_sizes, int n_in,
                              void* d_out, int out_size, void* d_ws, size_t ws_size,
                              hipStream_t stream) {
  const int*   sup_in  = (const int*)d_in[0];
  const int*   sup_out = (const int*)d_in[1];
  const int*   qry_in  = (const int*)d_in[2];
  const int*   sup_msk = (const int*)d_in[3];
  const float* emb     = (const float*)d_in[4];
  const float* Wqkv    = (const float*)d_in[5];
  const float* bqkv    = (const float*)d_in[6];
  const float* Wo      = (const float*)d_in[7];
  const float* bo      = (const float*)d_in[8];
  const float* ln1s    = (const float*)d_in[9];
  const float* ln1b    = (const float*)d_in[10];
  const float* W1      = (const float*)d_in[11];
  const float* b1      = (const float*)d_in[12];
  const float* W2      = (const float*)d_in[13];
  const float* b2      = (const float*)d_in[14];
  const float* ln2s    = (const float*)d_in[15];
  const float* ln2b    = (const float*)d_in[16];
  const float* Wp      = (const float*)d_in[17];
  const float* bp      = (const float*)d_in[18];

  // bf16 stream: xb[NTOK,128] | yb[NTOK,128] | U[NTOK,384] | weights | proto scratch
  u16* xb = (u16*)d_ws;
  u16* yb = xb + (size_t)NTOK * D;
  u16* U  = yb + (size_t)NTOK * D;
  u16* qkvb  = U;                                // [NTOK,384]
  u16* midb  = U;                                // [NTOK,256] (qkvb dead)
  u16* featb = U;                                // [NTOK,256]
  u16* wqkvb = U + (size_t)NTOK * 384;
  u16* wob   = wqkvb + 3 * 384 * 128;
  u16* w1b   = wob + 3 * 128 * 128;
  u16* w2b   = w1b + 3 * 256 * 128;
  u16* wpb   = w2b + 3 * 128 * 256;
  float* psum  = (float*)(((size_t)(wpb + 256 * 128) + 15) & ~(size_t)15);
  int*   pcnt  = (int*)(psum + NC * HF);
  float* outp = (float*)d_out;

  constexpr size_t GEMM_LDS = 65536;   // 2 x 4 x [128][32] u16

  hipMemsetAsync(psum, 0, NC * HF * sizeof(float) + 16 * sizeof(int), stream);

  // setup: weight conversion (1664 blocks) + embedding (16640 blocks)
  k_setup<<<dim3(1664 + 16640), 256, 0, stream>>>(
      Wqkv, Wo, W1, W2, Wp, wqkvb, sup_in, qry_in, emb, (u32*)xb);

  for (int l = 0; l < NL; ++l) {
    // QKV: xb -> qkvb
    k_gemm_mfma<false, true><<<dim3(3, NTOK / 128), 256, GEMM_LDS, stream>>>(
        xb, wqkvb + (size_t)l * 384 * 128, bqkv + l * 384, qkvb, NTOK, 384, D);
    // attention: qkvb -> yb (dual q-tile)
    k_attn_mfma<<<dim3(1152), 256, 0, stream>>>(qkvb, yb);
    // Wo + residual + LN1 (in place on xb)
    k_gemm_ln<<<dim3(NTOK / 128), 256, GEMM_LDS, stream>>>(
        yb, wob + (size_t)l * 128 * 128, bo + l * D, xb,
        ln1s + l * D, ln1b + l * D, NTOK, D);
    // W1 (+relu): xb -> midb
    k_gemm_mfma<true, true><<<dim3(2, NTOK / 128), 256, GEMM_LDS, stream>>>(
        xb, w1b + (size_t)l * 256 * 128, b1 + l * HF, midb, NTOK, HF, D);
    // W2 + residual + LN2 (in place on xb)
    k_gemm_ln<<<dim3(NTOK / 128), 256, GEMM_LDS, stream>>>(
        midb, w2b + (size_t)l * 128 * 256, b2 + l * D, xb,
        ln2s + l * D, ln2b + l * D, NTOK, HF);
  }

  // final projection: xb -> featb
  k_gemm_mfma<false, true><<<dim3(2, NTOK / 128), 256, GEMM_LDS, stream>>>(
      xb, wpb, bp, featb, NTOK, HF, D);
  k_proto_accum<<<dim3(NSUP / 256), 256, 0, stream>>>(featb, sup_out, sup_msk, psum, pcnt);
  k_logits<<<dim3((SEQ * NC + 255) / 256), 256, 0, stream>>>(featb, psum, pcnt, outp);
}